// Round 2
// baseline (136.854 us; speedup 1.0000x reference)
//
#include <hip/hip_runtime.h>

// KNNInteractionGraph: N=8192 atoms, K=32 neighbors, CUTOFF=10, NUM_MOLS=128,
// batch sorted -> each molecule is a contiguous index range (~64 atoms).
// Reference masks diag/cross-molecule/d>CUTOFF to CUTOFF, then top_k(-pdist,K).
// Only in-molecule pairs matter: O(sum n_b^2) ~ 0.5M vs reference's 67M.
//
// Output buffer: float32, 3*N*K elements, concatenated flat in return order:
//   [0      , N*K)   edge_index row 0 = neighbor indices
//   [N*K    , 2*N*K) edge_index row 1 = center row i
//   [2*N*K  , 3*N*K) edge_weight  (distance; CUTOFF for masked/fill slots)

#define CUTOFF_F 10.0f
#define NUM_MOLS 128
#define VCAP 120   // LDS distance-matrix cap: 120*120*4 = 57.6 KB static LDS

// Reference-exact masked distance:
//   sq = (sqn_r + sqn_c) - 2*dot   (gram expansion, f32, no FMA contraction)
//   sq = max(sq, 0); d = sq > 0 ? sqrt(sq) : 0
//   v  = (diag || d > CUTOFF) ? CUTOFF : d
__device__ __forceinline__ float dist_v(float4 pr, float4 pc, bool diag) {
    if (diag) return CUTOFF_F;
    float dot = __fadd_rn(__fadd_rn(__fmul_rn(pr.x, pc.x), __fmul_rn(pr.y, pc.y)),
                          __fmul_rn(pr.z, pc.z));
    float sq = __fsub_rn(__fadd_rn(pr.w, pc.w), __fadd_rn(dot, dot)); // 2*dot exact
    sq = fmaxf(sq, 0.0f);
    float d = (sq > 0.0f) ? __fsqrt_rn(sq) : 0.0f;
    return (d > CUTOFF_F) ? CUTOFF_F : d;
}

__device__ __forceinline__ float4 load_pos4(const float* __restrict__ pos, int g) {
    float x = pos[g * 3 + 0];
    float y = pos[g * 3 + 1];
    float z = pos[g * 3 + 2];
    float sq = __fadd_rn(__fadd_rn(__fmul_rn(x, x), __fmul_rn(y, y)), __fmul_rn(z, z));
    return make_float4(x, y, z, sq);
}

__global__ __launch_bounds__(256)
void knn_graph_kernel(const float* __restrict__ pos,
                      const int* __restrict__ batch,
                      float* __restrict__ out,
                      int N, int K) {
    const int b   = blockIdx.x;
    const int tid = threadIdx.x;
    const int NT  = blockDim.x;

    __shared__ int s_range[2];
    __shared__ float4 spos[VCAP];
    __shared__ float sv[VCAP * VCAP];

    if (tid == 0) {
        // lower_bound(batch, b) / lower_bound(batch, b+1) over sorted batch
        int lo = 0, hi = N;
        while (lo < hi) { int mid = (lo + hi) >> 1; if (batch[mid] < b) lo = mid + 1; else hi = mid; }
        s_range[0] = lo;
        lo = 0; hi = N;
        while (lo < hi) { int mid = (lo + hi) >> 1; if (batch[mid] < b + 1) lo = mid + 1; else hi = mid; }
        s_range[1] = lo;
    }
    __syncthreads();

    const int start = s_range[0];
    const int end   = s_range[1];
    const int n     = end - start;
    if (n <= 0) return;

    const int NK = N * K;

    // edge_index row 1: center rows (covers exactly [start*K, end*K))
    for (int t = tid; t < n * K; t += NT) {
        int i = start + t / K;
        out[NK + start * K + t] = (float)i;
    }

    if (n <= VCAP) {
        // ---- fast path: LDS-cached positions + full masked-distance matrix ----
        for (int c = tid; c < n; c += NT) spos[c] = load_pos4(pos, start + c);
        __syncthreads();

        const int nn = n * n;
        for (int p = tid; p < nn; p += NT) {
            int r = p / n, c = p - r * n;
            sv[r * n + c] = dist_v(spos[r], spos[c], r == c);
        }
        __syncthreads();

        // rank-selection: candidate (r,c) with v < CUTOFF goes to slot rank(v,c)
        for (int p = tid; p < nn; p += NT) {
            int r = p / n, c = p - r * n;
            float v = sv[r * n + c];
            if (v < CUTOFF_F) {
                const float* row = &sv[r * n];
                int rank = 0;
                for (int cc = 0; cc < n; ++cc) {
                    float vv = row[cc];
                    rank += (vv < v) || (vv == v && cc < c);   // stable: (v asc, idx asc)
                }
                if (rank < K) {
                    int o = (start + r) * K + rank;
                    out[o]          = (float)(start + c);
                    out[2 * NK + o] = v;
                }
            }
        }
        __syncthreads();

        // fill: rows with m < K valid neighbors get CUTOFF entries at the
        // globally-smallest masked indices (lax.top_k tie order: value asc, idx asc)
        for (int r = tid; r < n; r += NT) {
            const float* row = &sv[r * n];
            int m = 0;
            for (int c = 0; c < n; ++c) m += (row[c] < CUTOFF_F);
            if (m < K) {
                int s = m, j = 0;
                while (s < K) {
                    bool masked = (j < start || j >= end) ? true
                                                          : (row[j - start] == CUTOFF_F);
                    if (masked) {
                        int o = (start + r) * K + s;
                        out[o]          = (float)j;
                        out[2 * NK + o] = CUTOFF_F;
                        ++s;
                    }
                    ++j;
                }
            }
        }
    } else {
        // ---- fallback (n > VCAP): global-memory recompute, correct for any n ----
        const int nn = n * n;
        for (int p = tid; p < nn; p += NT) {
            int r = p / n, c = p - r * n;
            float4 pr = load_pos4(pos, start + r);
            float v = dist_v(pr, load_pos4(pos, start + c), r == c);
            if (v < CUTOFF_F) {
                int rank = 0;
                for (int cc = 0; cc < n; ++cc) {
                    float vv = dist_v(pr, load_pos4(pos, start + cc), r == cc);
                    rank += (vv < v) || (vv == v && cc < c);
                }
                if (rank < K) {
                    int o = (start + r) * K + rank;
                    out[o]          = (float)(start + c);
                    out[2 * NK + o] = v;
                }
            }
        }
        for (int r = tid; r < n; r += NT) {
            float4 pr = load_pos4(pos, start + r);
            int m = 0;
            for (int c = 0; c < n; ++c)
                m += (dist_v(pr, load_pos4(pos, start + c), r == c) < CUTOFF_F);
            if (m < K) {
                int s = m, j = 0;
                while (s < K) {
                    bool masked = (j < start || j >= end)
                        ? true
                        : (dist_v(pr, load_pos4(pos, j), r == (j - start)) == CUTOFF_F);
                    if (masked) {
                        int o = (start + r) * K + s;
                        out[o]          = (float)j;
                        out[2 * NK + o] = CUTOFF_F;
                        ++s;
                    }
                    ++j;
                }
            }
        }
    }
}

extern "C" void kernel_launch(void* const* d_in, const int* in_sizes, int n_in,
                              void* d_out, int out_size, void* d_ws, size_t ws_size,
                              hipStream_t stream) {
    const float* pos   = (const float*)d_in[0];   // [N,3] float32
    const int*   batch = (const int*)d_in[1];     // [N]   int32, sorted
    float*       out   = (float*)d_out;           // float32, 3*N*K elements

    const int N = in_sizes[1];            // 8192
    const int K = out_size / (3 * N);     // 32

    knn_graph_kernel<<<NUM_MOLS, 256, 0, stream>>>(pos, batch, out, N, K);
}

// Round 3
// 72.720 us; speedup vs baseline: 1.8819x; 1.8819x over previous
//
#include <hip/hip_runtime.h>

// KNNInteractionGraph — row-centric decomposition.
// N=8192 atoms, K=32, CUTOFF=10, batch sorted (molecules = contiguous ranges,
// ~64 atoms each). One WAVE per row r: compute the row's masked distances to
// its molecule, stable rank-select top-K, CUTOFF-tie fill. 2048 blocks x 256
// threads = 8192 waves (vs 128 blocks in round 2 -> was 2.8% occupancy).
//
// Output buffer: float32, 3*N*K elements, flat in return order:
//   [0      , N*K)   edge_index row 0 = neighbor indices
//   [N*K    , 2*N*K) edge_index row 1 = center row i
//   [2*N*K  , 3*N*K) edge_weight

#define CUTOFF_F 10.0f
#define SDMAX 256           // per-wave LDS row buffer (floats); covers n<=256
#define ROWS_PER_BLOCK 4    // 4 waves/block

// Reference-exact masked distance (gram expansion, f32, no FMA contraction):
__device__ __forceinline__ float dist_v(float4 pr, float4 pc, bool diag) {
    if (diag) return CUTOFF_F;
    float dot = __fadd_rn(__fadd_rn(__fmul_rn(pr.x, pc.x), __fmul_rn(pr.y, pc.y)),
                          __fmul_rn(pr.z, pc.z));
    float sq = __fsub_rn(__fadd_rn(pr.w, pc.w), __fadd_rn(dot, dot));
    sq = fmaxf(sq, 0.0f);
    float d = (sq > 0.0f) ? __fsqrt_rn(sq) : 0.0f;
    return (d > CUTOFF_F) ? CUTOFF_F : d;
}

__device__ __forceinline__ float4 load_pos4(const float* __restrict__ pos, int g) {
    float x = pos[g * 3 + 0];
    float y = pos[g * 3 + 1];
    float z = pos[g * 3 + 2];
    float sq = __fadd_rn(__fadd_rn(__fmul_rn(x, x), __fmul_rn(y, y)), __fmul_rn(z, z));
    return make_float4(x, y, z, sq);
}

// Fill slots [m, K) with CUTOFF entries at the globally-smallest masked
// indices: {0..start-1} U {in-mol masked (srow==CUTOFF)} U {end..N-1}.
// `masked_lookup(cc)` tells whether in-mol column cc is masked.
template <typename MaskF>
__device__ __forceinline__ void do_fill(int m, int K, int lane, int start, int end,
                                        int n, int r, int NK,
                                        float* __restrict__ out, MaskF masked_at) {
    const int mm = n - m;  // in-mol masked count (incl diagonal)
    for (int fbase = 0; fbase < K - m; fbase += 64) {
        const int t = fbase + lane;           // t-th masked index -> slot m+t
        const bool active = t < (K - m);
        int idx = 0;
        bool found = false;
        if (active) {
            if (t < start)              { idx = t;                        found = true; }
            else if (t - start >= mm)   { idx = end + (t - start - mm);   found = true; }
        }
        if (__any(active && !found)) {
            int cnt = 0;
            for (int cc = 0; cc < n; ++cc) {
                if (masked_at(cc)) {
                    if (active && !found && cnt == t - start) { idx = start + cc; found = true; }
                    ++cnt;
                }
            }
        }
        if (active) {
            int o = r * K + m + t;
            out[o]          = (float)idx;
            out[2 * NK + o] = CUTOFF_F;
        }
    }
}

// LDS-path core: candidates for this wave's row live in srow[0..n). Each lane
// owns columns c = lane + 64*j (j < NCH). One lockstep sweep over cc computes
// all ranks (stable: value asc, index asc). srow[cc] is wave-uniform ->
// LDS broadcast, conflict-free.
template <int NCH>
__device__ __forceinline__ void row_core(const float* __restrict__ srow, int n,
                                         int lane, int start, int end, int r,
                                         float* __restrict__ out, int NK, int K) {
    float vr[NCH];
    int   rk[NCH];
#pragma unroll
    for (int j = 0; j < NCH; ++j) {
        int c = lane + 64 * j;
        vr[j] = (c < n) ? srow[c] : CUTOFF_F;
        rk[j] = 0;
    }
#pragma unroll 4
    for (int cc = 0; cc < n; ++cc) {
        float vv = srow[cc];
#pragma unroll
        for (int j = 0; j < NCH; ++j) {
            int c = lane + 64 * j;
            rk[j] += (vv < vr[j]) || (vv == vr[j] && cc < c);
        }
    }
    int m = 0;
#pragma unroll
    for (int j = 0; j < NCH; ++j) {
        int c = lane + 64 * j;
        m += __popcll(__ballot(c < n && vr[j] < CUTOFF_F));
    }
#pragma unroll
    for (int j = 0; j < NCH; ++j) {
        int c = lane + 64 * j;
        if (c < n && vr[j] < CUTOFF_F && rk[j] < K) {
            int o = r * K + rk[j];
            out[o]          = (float)(start + c);
            out[2 * NK + o] = vr[j];
        }
    }
    for (int k2 = lane; k2 < K; k2 += 64)  // edge_index row 1 (center)
        out[NK + r * K + k2] = (float)r;
    if (m < K)
        do_fill(m, K, lane, start, end, n, r, NK, out,
                [&](int cc) { return srow[cc] == CUTOFF_F; });
}

__global__ __launch_bounds__(256)
void knn_rows_kernel(const float* __restrict__ pos,
                     const int* __restrict__ batch,
                     float* __restrict__ out,
                     int N, int K) {
    __shared__ float sd[ROWS_PER_BLOCK][SDMAX];
    const int w    = threadIdx.x >> 6;
    const int lane = threadIdx.x & 63;
    // Clamp instead of early-return so __syncthreads is always block-uniform
    // (duplicate waves rewrite identical values; benign).
    const int r = min(blockIdx.x * ROWS_PER_BLOCK + w, N - 1);
    const int NK = N * K;

    const int b = batch[r];
    // start = lower_bound(batch, b) in [0, r]; end = lower_bound(batch, b+1) in [r+1, N]
    int lo = 0, hi = r;
    while (lo < hi) { int mid = (lo + hi) >> 1; if (batch[mid] < b) lo = mid + 1; else hi = mid; }
    const int start = lo;
    lo = r + 1; hi = N;
    while (lo < hi) { int mid = (lo + hi) >> 1; if (batch[mid] < b + 1) lo = mid + 1; else hi = mid; }
    const int end = lo;
    const int n = end - start;

    const float4 pr = load_pos4(pos, r);
    const bool lds_ok = (n <= SDMAX);

    if (lds_ok) {
        float* srow = sd[w];
        for (int c = lane; c < n; c += 64)
            srow[c] = dist_v(pr, load_pos4(pos, start + c), (start + c) == r);
    }
    __syncthreads();  // orders each wave's LDS writes before its reads (block-uniform)

    if (lds_ok) {
        const float* srow = sd[w];
        if (n <= 64)        row_core<1>(srow, n, lane, start, end, r, out, NK, K);
        else if (n <= 128)  row_core<2>(srow, n, lane, start, end, r, out, NK, K);
        else                row_core<4>(srow, n, lane, start, end, r, out, NK, K);
    } else {
        // Fallback (n > SDMAX): recompute distances on the fly. Correct for any
        // n; never taken with the bench inputs (n ~ 64-90).
        int m = 0;
        for (int cbase = 0; cbase < n; cbase += 64) {
            const int c = cbase + lane;
            float v = (c < n) ? dist_v(pr, load_pos4(pos, start + c), (start + c) == r)
                              : CUTOFF_F;
            int rk = 0;
            for (int cc = 0; cc < n; ++cc) {
                float vv = dist_v(pr, load_pos4(pos, start + cc), (start + cc) == r);
                rk += (vv < v) || (vv == v && cc < c);
            }
            if (c < n && v < CUTOFF_F && rk < K) {
                int o = r * K + rk;
                out[o]          = (float)(start + c);
                out[2 * NK + o] = v;
            }
            m += __popcll(__ballot(c < n && v < CUTOFF_F));
        }
        for (int k2 = lane; k2 < K; k2 += 64)
            out[NK + r * K + k2] = (float)r;
        if (m < K)
            do_fill(m, K, lane, start, end, n, r, NK, out, [&](int cc) {
                return dist_v(pr, load_pos4(pos, start + cc), (start + cc) == r) == CUTOFF_F;
            });
    }
}

extern "C" void kernel_launch(void* const* d_in, const int* in_sizes, int n_in,
                              void* d_out, int out_size, void* d_ws, size_t ws_size,
                              hipStream_t stream) {
    const float* pos   = (const float*)d_in[0];   // [N,3] float32
    const int*   batch = (const int*)d_in[1];     // [N]   int32, sorted
    float*       out   = (float*)d_out;           // float32, 3*N*K

    const int N = in_sizes[1];            // 8192
    const int K = out_size / (3 * N);     // 32

    const int grid = (N + ROWS_PER_BLOCK - 1) / ROWS_PER_BLOCK;  // 2048
    knn_rows_kernel<<<grid, 256, 0, stream>>>(pos, batch, out, N, K);
}

// Round 4
// 67.673 us; speedup vs baseline: 2.0223x; 1.0746x over previous
//
#include <hip/hip_runtime.h>

// KNNInteractionGraph — row-per-wave, register-only rank selection.
// N=8192, K=32, CUTOFF=10, batch sorted (molecules contiguous, n ~ 64+-8).
//
// Kernel A (prepass): mol_start[0..NUM_MOLS] lower-bounds into d_ws, and the
//   centers chunk out[NK..2NK) (coalesced).
// Kernel B: one wave per row r. Lane owns column c = 64j+lane, distance in
//   registers; stable rank via v_readlane broadcast sweep (no LDS, no barrier).
//
// Output (float32, 3*N*K): [indices | centers | weights].

#define CUTOFF_F 10.0f
#define NUM_MOLS 128
#define ROWS_PER_BLOCK 4

__device__ __forceinline__ float readlane_f(float v, int lane) {
    return __int_as_float(__builtin_amdgcn_readlane(__float_as_int(v), lane));
}

// Reference-exact masked distance (gram expansion, f32, no FMA contraction):
__device__ __forceinline__ float dist_v(float4 pr, float4 pc, bool diag) {
    if (diag) return CUTOFF_F;
    float dot = __fadd_rn(__fadd_rn(__fmul_rn(pr.x, pc.x), __fmul_rn(pr.y, pc.y)),
                          __fmul_rn(pr.z, pc.z));
    float sq = __fsub_rn(__fadd_rn(pr.w, pc.w), __fadd_rn(dot, dot));
    sq = fmaxf(sq, 0.0f);
    float d = (sq > 0.0f) ? __fsqrt_rn(sq) : 0.0f;
    return (d > CUTOFF_F) ? CUTOFF_F : d;
}

__device__ __forceinline__ float4 load_pos4(const float* __restrict__ pos, int g) {
    float x = pos[g * 3 + 0];
    float y = pos[g * 3 + 1];
    float z = pos[g * 3 + 2];
    float sq = __fadd_rn(__fadd_rn(__fmul_rn(x, x), __fmul_rn(y, y)), __fmul_rn(z, z));
    return make_float4(x, y, z, sq);
}

// ---------------- Kernel A: molecule boundaries + centers chunk ----------------
__global__ __launch_bounds__(256)
void knn_prepass(const int* __restrict__ batch, int* __restrict__ ms,
                 float* __restrict__ out, int N, int K) {
    const int t = blockIdx.x * blockDim.x + threadIdx.x;
    const int NK = N * K;
    if (t < NK) out[NK + t] = (float)(t / K);   // centers: row index of edge t
    if (t < N) {
        const int bi = batch[t];
        const int bp = (t == 0) ? -1 : batch[t - 1];
        for (int b = bp + 1; b <= bi; ++b) ms[b] = t;      // lower_bound(batch,b)=t
        if (t == N - 1)
            for (int b = bi + 1; b <= NUM_MOLS; ++b) ms[b] = N;
    }
}

// ---------------- Kernel B row core (register-only, n <= 64*NCH) ----------------
template <int NCH>
__device__ __forceinline__ void row_core_reg(const float* __restrict__ pos,
                                             float4 pr, int n, int lane,
                                             int start, int end, int r,
                                             float* __restrict__ out,
                                             int NK, int K) {
    float v[NCH];
    int   rk[NCH];
#pragma unroll
    for (int j = 0; j < NCH; ++j) {
        const int c = 64 * j + lane;
        v[j]  = (c < n) ? dist_v(pr, load_pos4(pos, start + c), (start + c) == r)
                        : CUTOFF_F;
        rk[j] = 0;
    }
    // stable rank sweep: broadcast column g's value via readlane (uniform lane idx)
#pragma unroll
    for (int jj = 0; jj < NCH; ++jj) {
        const int base = 64 * jj;
        const int lim  = (NCH == 1) ? n : min(n - base, 64);  // >0 by NCH selection
#pragma unroll 4
        for (int cc = 0; cc < lim; ++cc) {
            const float vv = readlane_f(v[jj], cc);
            const int   g  = base + cc;
#pragma unroll
            for (int j = 0; j < NCH; ++j) {
                const int c = 64 * j + lane;
                rk[j] += (vv < v[j]) || (vv == v[j] && g < c);  // (value asc, idx asc)
            }
        }
    }
    int m = 0;
#pragma unroll
    for (int j = 0; j < NCH; ++j) {
        const int c = 64 * j + lane;
        m += __popcll(__ballot(c < n && v[j] < CUTOFF_F));
    }
#pragma unroll
    for (int j = 0; j < NCH; ++j) {
        const int c = 64 * j + lane;
        if (c < n && v[j] < CUTOFF_F && rk[j] < K) {
            const int o = r * K + rk[j];
            out[o]          = (float)(start + c);
            out[2 * NK + o] = v[j];
        }
    }
    // fill slots [m,K) with CUTOFF at globally-smallest masked indices:
    // {0..start-1} U {in-mol masked} U {end..N-1}  (lax.top_k tie order)
    if (m < K) {
        const int mm = n - m;   // in-mol masked count (incl diagonal)
        for (int fb = 0; fb < K - m; fb += 64) {
            const int t = fb + lane;
            const bool active = t < (K - m);
            int idx = 0;
            bool found = false;
            if (active) {
                if (t < start)            { idx = t;                      found = true; }
                else if (t - start >= mm) { idx = end + (t - start - mm); found = true; }
            }
            if (__any(active && !found)) {
                int cnt = 0;
#pragma unroll
                for (int jj = 0; jj < NCH; ++jj) {
                    const int base = 64 * jj;
                    const int lim  = min(n - base, 64);
                    for (int cc = 0; cc < lim; ++cc) {
                        if (readlane_f(v[jj], cc) == CUTOFF_F) {
                            if (active && !found && cnt == t - start) {
                                idx = start + base + cc; found = true;
                            }
                            ++cnt;
                        }
                    }
                }
            }
            if (active) {
                const int o = r * K + m + t;
                out[o]          = (float)idx;
                out[2 * NK + o] = CUTOFF_F;
            }
        }
    }
}

// ---------------- Kernel B ----------------
__global__ __launch_bounds__(256, 8)
void knn_rows_kernel(const float* __restrict__ pos,
                     const int* __restrict__ batch,
                     const int* __restrict__ ms,
                     float* __restrict__ out,
                     int N, int K) {
    const int w    = threadIdx.x >> 6;
    const int lane = threadIdx.x & 63;
    const int r    = blockIdx.x * ROWS_PER_BLOCK + w;
    if (r >= N) return;            // no LDS, no barriers -> early return is safe
    const int NK = N * K;

    const int b     = batch[r];
    const int start = ms[b];
    const int end   = ms[b + 1];
    const int n     = end - start;

    const float4 pr = load_pos4(pos, r);

    if      (n <= 64)  row_core_reg<1>(pos, pr, n, lane, start, end, r, out, NK, K);
    else if (n <= 128) row_core_reg<2>(pos, pr, n, lane, start, end, r, out, NK, K);
    else if (n <= 192) row_core_reg<3>(pos, pr, n, lane, start, end, r, out, NK, K);
    else if (n <= 256) row_core_reg<4>(pos, pr, n, lane, start, end, r, out, NK, K);
    else {
        // fallback (n > 256): global recompute; correct for any n, never taken here
        int m = 0;
        for (int cb = 0; cb < n; cb += 64) {
            const int c = cb + lane;
            const float v = (c < n)
                ? dist_v(pr, load_pos4(pos, start + c), (start + c) == r) : CUTOFF_F;
            int rk = 0;
            for (int cc = 0; cc < n; ++cc) {
                const float vv = dist_v(pr, load_pos4(pos, start + cc), (start + cc) == r);
                rk += (vv < v) || (vv == v && cc < c);
            }
            if (c < n && v < CUTOFF_F && rk < K) {
                const int o = r * K + rk;
                out[o]          = (float)(start + c);
                out[2 * NK + o] = v;
            }
            m += __popcll(__ballot(c < n && v < CUTOFF_F));
        }
        if (m < K) {
            const int mm = n - m;
            for (int fb = 0; fb < K - m; fb += 64) {
                const int t = fb + lane;
                const bool active = t < (K - m);
                int idx = 0; bool found = false;
                if (active) {
                    if (t < start)            { idx = t;                      found = true; }
                    else if (t - start >= mm) { idx = end + (t - start - mm); found = true; }
                }
                if (__any(active && !found)) {
                    int cnt = 0;
                    for (int cc = 0; cc < n; ++cc) {
                        if (dist_v(pr, load_pos4(pos, start + cc), (start + cc) == r)
                            == CUTOFF_F) {
                            if (active && !found && cnt == t - start) {
                                idx = start + cc; found = true;
                            }
                            ++cnt;
                        }
                    }
                }
                if (active) {
                    const int o = r * K + m + t;
                    out[o]          = (float)idx;
                    out[2 * NK + o] = CUTOFF_F;
                }
            }
        }
    }
}

extern "C" void kernel_launch(void* const* d_in, const int* in_sizes, int n_in,
                              void* d_out, int out_size, void* d_ws, size_t ws_size,
                              hipStream_t stream) {
    const float* pos   = (const float*)d_in[0];   // [N,3] float32
    const int*   batch = (const int*)d_in[1];     // [N]   int32, sorted
    float*       out   = (float*)d_out;           // float32, 3*N*K
    int*         ms    = (int*)d_ws;              // mol_start[NUM_MOLS+1]

    const int N = in_sizes[1];            // 8192
    const int K = out_size / (3 * N);     // 32

    const int gridA = (N * K + 255) / 256;                       // covers NK and N
    knn_prepass<<<gridA, 256, 0, stream>>>(batch, ms, out, N, K);

    const int gridB = (N + ROWS_PER_BLOCK - 1) / ROWS_PER_BLOCK; // 2048
    knn_rows_kernel<<<gridB, 256, 0, stream>>>(pos, batch, ms, out, N, K);
}

// Round 5
// 66.334 us; speedup vs baseline: 2.0631x; 1.0202x over previous
//
#include <hip/hip_runtime.h>

// KNNInteractionGraph — single fused kernel, row-per-wave.
// N=8192, K=32, CUTOFF=10, batch sorted (molecules contiguous, n ~ 64+-8).
//
// One wave per row r:
//   - molecule range [start,end) found by ballot window-scan over batch
//     (2 coalesced loads; no prepass table, no binary search in the hot path)
//   - lane owns column c = 64j+lane, distance kept in registers
//   - stable rank (value asc, index asc) via v_readlane broadcast sweep
//   - writes its K outputs: indices, centers, weights
//
// Output (float32, 3*N*K): [indices | centers | weights].

#define CUTOFF_F 10.0f
#define ROWS_PER_BLOCK 4

__device__ __forceinline__ float readlane_f(float v, int lane) {
    return __int_as_float(__builtin_amdgcn_readlane(__float_as_int(v), lane));
}
__device__ __forceinline__ int readlane_i(int v, int lane) {
    return __builtin_amdgcn_readlane(v, lane);
}

// Reference-exact masked distance (gram expansion, f32, no FMA contraction):
__device__ __forceinline__ float dist_v(float4 pr, float4 pc, bool diag) {
    if (diag) return CUTOFF_F;
    float dot = __fadd_rn(__fadd_rn(__fmul_rn(pr.x, pc.x), __fmul_rn(pr.y, pc.y)),
                          __fmul_rn(pr.z, pc.z));
    float sq = __fsub_rn(__fadd_rn(pr.w, pc.w), __fadd_rn(dot, dot));
    sq = fmaxf(sq, 0.0f);
    float d = (sq > 0.0f) ? __fsqrt_rn(sq) : 0.0f;
    return (d > CUTOFF_F) ? CUTOFF_F : d;
}

__device__ __forceinline__ float4 load_pos4(const float* __restrict__ pos, int g) {
    float x = pos[g * 3 + 0];
    float y = pos[g * 3 + 1];
    float z = pos[g * 3 + 2];
    float sq = __fadd_rn(__fadd_rn(__fmul_rn(x, x), __fmul_rn(y, y)), __fmul_rn(z, z));
    return make_float4(x, y, z, sq);
}

// Row core: columns in registers, n <= 64*NCH.
template <int NCH>
__device__ __forceinline__ void row_core_reg(const float* __restrict__ pos,
                                             float4 pr, int n, int lane,
                                             int start, int end, int r,
                                             float* __restrict__ out,
                                             int NK, int K) {
    float v[NCH];
    int   rk[NCH];
#pragma unroll
    for (int j = 0; j < NCH; ++j) {
        const int c = 64 * j + lane;
        v[j]  = (c < n) ? dist_v(pr, load_pos4(pos, start + c), (start + c) == r)
                        : CUTOFF_F;
        rk[j] = 0;
    }
    // stable rank sweep: broadcast column g's value (uniform lane index)
#pragma unroll
    for (int jj = 0; jj < NCH; ++jj) {
        const int base = 64 * jj;
        const int lim  = (NCH == 1) ? n : min(n - base, 64);
#pragma unroll 4
        for (int cc = 0; cc < lim; ++cc) {
            const float vv = readlane_f(v[jj], cc);
            const int   g  = base + cc;
#pragma unroll
            for (int j = 0; j < NCH; ++j) {
                const int c = 64 * j + lane;
                rk[j] += (vv < v[j]) || (vv == v[j] && g < c);  // (value asc, idx asc)
            }
        }
    }
    int m = 0;
#pragma unroll
    for (int j = 0; j < NCH; ++j) {
        const int c = 64 * j + lane;
        m += __popcll(__ballot(c < n && v[j] < CUTOFF_F));
    }
#pragma unroll
    for (int j = 0; j < NCH; ++j) {
        const int c = 64 * j + lane;
        if (c < n && v[j] < CUTOFF_F && rk[j] < K) {
            const int o = r * K + rk[j];
            out[o]          = (float)(start + c);
            out[2 * NK + o] = v[j];
        }
    }
    for (int k2 = lane; k2 < K; k2 += 64)     // centers chunk
        out[NK + r * K + k2] = (float)r;
    // fill slots [m,K): CUTOFF at globally-smallest masked indices
    // {0..start-1} U {in-mol masked} U {end..N-1}  (lax.top_k tie order)
    if (m < K) {
        const int mm = n - m;                 // in-mol masked count (incl diag)
        for (int fb = 0; fb < K - m; fb += 64) {
            const int t = fb + lane;
            const bool active = t < (K - m);
            int idx = 0;
            bool found = false;
            if (active) {
                if (t < start)            { idx = t;                      found = true; }
                else if (t - start >= mm) { idx = end + (t - start - mm); found = true; }
            }
            if (__any(active && !found)) {
                int cnt = 0;
#pragma unroll
                for (int jj = 0; jj < NCH; ++jj) {
                    const int base = 64 * jj;
                    const int lim  = min(n - base, 64);
                    for (int cc = 0; cc < lim; ++cc) {
                        if (readlane_f(v[jj], cc) == CUTOFF_F) {
                            if (active && !found && cnt == t - start) {
                                idx = start + base + cc; found = true;
                            }
                            ++cnt;
                        }
                    }
                }
            }
            if (active) {
                const int o = r * K + m + t;
                out[o]          = (float)idx;
                out[2 * NK + o] = CUTOFF_F;
            }
        }
    }
}

__global__ __launch_bounds__(256, 8)
void knn_fused_kernel(const float* __restrict__ pos,
                      const int* __restrict__ batch,
                      float* __restrict__ out,
                      int N, int K) {
    const int w    = threadIdx.x >> 6;
    const int lane = threadIdx.x & 63;
    const int r    = blockIdx.x * ROWS_PER_BLOCK + w;
    if (r >= N) return;                       // no LDS, no barriers
    const int NK = N * K;

    // --- issue all independent loads up front (chain depth 1) ---
    const int iu = r - 63 + lane;             // upward window: idx r-63 .. r
    const int id = r + 1 + lane;              // downward window: idx r+1 .. r+64
    const int au = batch[max(iu, 0)];
    const int ad = batch[min(id, N - 1)];
    const float4 pr = load_pos4(pos, r);

    const int b = readlane_i(au, 63);         // batch[r]

    // start: leading-ones run of the upward match mask
    const unsigned long long mu = __ballot(iu >= 0 && au == b);   // bit63 always set
    int start;
    if (mu != ~0ull) {
        start = r - __builtin_clzll(~mu) + 1;
    } else {
        const int iu2 = r - 127 + lane;
        const unsigned long long mu2 =
            __ballot(iu2 >= 0 && batch[max(iu2, 0)] == b);
        if (mu2 != ~0ull) {
            start = r - 63 - __builtin_clzll(~mu2);
        } else if (r - 127 <= 0) {
            start = 0;
        } else {                              // n > 128 upward: binary search (cold)
            int lo = 0, hi = r;
            while (lo < hi) { int mid = (lo + hi) >> 1;
                              if (batch[mid] < b) lo = mid + 1; else hi = mid; }
            start = lo;
        }
    }

    // end: trailing-ones run of the downward match mask
    const unsigned long long md = __ballot(id < N && ad == b);
    int end;
    if (md != ~0ull) {
        end = r + 1 + __builtin_ctzll(~md);
    } else {
        const int id2 = r + 65 + lane;
        const unsigned long long md2 =
            __ballot(id2 < N && batch[min(id2, N - 1)] == b);
        if (md2 != ~0ull) {
            end = r + 65 + __builtin_ctzll(~md2);
        } else if (r + 129 >= N) {
            end = N;
        } else {                              // n > 128 downward: binary search (cold)
            int lo = r + 1, hi = N;
            while (lo < hi) { int mid = (lo + hi) >> 1;
                              if (batch[mid] < b + 1) lo = mid + 1; else hi = mid; }
            end = lo;
        }
    }

    const int n = end - start;

    if      (n <= 64)  row_core_reg<1>(pos, pr, n, lane, start, end, r, out, NK, K);
    else if (n <= 128) row_core_reg<2>(pos, pr, n, lane, start, end, r, out, NK, K);
    else if (n <= 192) row_core_reg<3>(pos, pr, n, lane, start, end, r, out, NK, K);
    else if (n <= 256) row_core_reg<4>(pos, pr, n, lane, start, end, r, out, NK, K);
    else {
        // fallback (n > 256): recompute on the fly; correct for any n, never taken
        int m = 0;
        for (int cb = 0; cb < n; cb += 64) {
            const int c = cb + lane;
            const float v = (c < n)
                ? dist_v(pr, load_pos4(pos, start + c), (start + c) == r) : CUTOFF_F;
            int rk = 0;
            for (int cc = 0; cc < n; ++cc) {
                const float vv = dist_v(pr, load_pos4(pos, start + cc), (start + cc) == r);
                rk += (vv < v) || (vv == v && cc < c);
            }
            if (c < n && v < CUTOFF_F && rk < K) {
                const int o = r * K + rk;
                out[o]          = (float)(start + c);
                out[2 * NK + o] = v;
            }
            m += __popcll(__ballot(c < n && v < CUTOFF_F));
        }
        for (int k2 = lane; k2 < K; k2 += 64)
            out[NK + r * K + k2] = (float)r;
        if (m < K) {
            const int mm = n - m;
            for (int fb = 0; fb < K - m; fb += 64) {
                const int t = fb + lane;
                const bool active = t < (K - m);
                int idx = 0; bool found = false;
                if (active) {
                    if (t < start)            { idx = t;                      found = true; }
                    else if (t - start >= mm) { idx = end + (t - start - mm); found = true; }
                }
                if (__any(active && !found)) {
                    int cnt = 0;
                    for (int cc = 0; cc < n; ++cc) {
                        if (dist_v(pr, load_pos4(pos, start + cc), (start + cc) == r)
                            == CUTOFF_F) {
                            if (active && !found && cnt == t - start) {
                                idx = start + cc; found = true;
                            }
                            ++cnt;
                        }
                    }
                }
                if (active) {
                    const int o = r * K + m + t;
                    out[o]          = (float)idx;
                    out[2 * NK + o] = CUTOFF_F;
                }
            }
        }
    }
}

extern "C" void kernel_launch(void* const* d_in, const int* in_sizes, int n_in,
                              void* d_out, int out_size, void* d_ws, size_t ws_size,
                              hipStream_t stream) {
    const float* pos   = (const float*)d_in[0];   // [N,3] float32
    const int*   batch = (const int*)d_in[1];     // [N]   int32, sorted
    float*       out   = (float*)d_out;           // float32, 3*N*K

    const int N = in_sizes[1];            // 8192
    const int K = out_size / (3 * N);     // 32

    const int grid = (N + ROWS_PER_BLOCK - 1) / ROWS_PER_BLOCK;  // 2048
    knn_fused_kernel<<<grid, 256, 0, stream>>>(pos, batch, out, N, K);
}